// Round 6
// baseline (143.123 us; speedup 1.0000x reference)
//
#include <hip/hip_runtime.h>
#include <math.h>

#define NSLOT 5
#define EPSF 1e-8f

typedef float f4 __attribute__((ext_vector_type(4)));

// ---------------- binning kernels ----------------

__global__ void hist_kernel(const int* __restrict__ labels, int* __restrict__ counts, int B) {
    int i = blockIdx.x * blockDim.x + threadIdx.x;
    if (i < B) atomicAdd(&counts[labels[i]], 1);
}

__global__ void scan_kernel(const int* __restrict__ counts, int* __restrict__ offsets,
                            int* __restrict__ cursor, int C) {
    __shared__ int sh[1024];
    __shared__ int running;
    if (threadIdx.x == 0) running = 0;
    __syncthreads();
    for (int base = 0; base < C; base += 1024) {
        int t = base + threadIdx.x;
        int v = (t < C) ? counts[t] : 0;
        sh[threadIdx.x] = v;
        __syncthreads();
        for (int d = 1; d < 1024; d <<= 1) {
            int x = (threadIdx.x >= d) ? sh[threadIdx.x - d] : 0;
            __syncthreads();
            sh[threadIdx.x] += x;
            __syncthreads();
        }
        int excl = sh[threadIdx.x] - v + running;
        if (t < C) { offsets[t] = excl; cursor[t] = excl; }
        __syncthreads();
        if (threadIdx.x == 0) running += sh[1023];
        __syncthreads();
    }
}

__global__ void scatter_kernel(const int* __restrict__ labels, int* __restrict__ cursor,
                               int* __restrict__ bucket, int B) {
    int i = blockIdx.x * blockDim.x + threadIdx.x;
    if (i < B) {
        int slot = atomicAdd(&cursor[labels[i]], 1);
        bucket[slot] = i;
    }
}

// ---------------- main class-centric kernel (D=2048) ----------------
// One block per class; keys staged in LDS once; 4 waves each take one sample.

__global__ __launch_bounds__(256, 4) void mb_class_kernel(
    const float* __restrict__ query,
    const float* __restrict__ mkeys,
    const float* __restrict__ mvals,
    const float* __restrict__ qscores,
    const int*   __restrict__ topk_p,
    const int*   __restrict__ counts,
    const int*   __restrict__ offsets,
    const int*   __restrict__ bucket,
    float* __restrict__ out_ret,
    float* __restrict__ out_w)
{
    const int c   = blockIdx.x;
    const int cnt = counts[c];
    if (cnt == 0) return;
    const int off  = offsets[c];
    const int lane = threadIdx.x & 63;
    const int wave = threadIdx.x >> 6;

    __shared__ f4 kls[NSLOT * 512];   // 40 KiB: the class's 5 key rows

    const f4* kc = reinterpret_cast<const f4*>(mkeys) + (size_t)c * NSLOT * 512;
    const f4* vc = reinterpret_cast<const f4*>(mvals) + (size_t)c * NSLOT * 512;

    for (int t = threadIdx.x; t < NSLOT * 512; t += 256)
        kls[t] = kc[t];
    __syncthreads();

    int k = topk_p[0];
    if (k > NSLOT) k = NSLOT;
    if (k < 1) k = 1;

    // per-class key-row norms (each wave computes its own copy from LDS)
    float kk[NSLOT];
#pragma unroll
    for (int s = 0; s < NSLOT; ++s) {
        float acc = 0.f;
#pragma unroll
        for (int m = 0; m < 8; ++m) {
            f4 t = kls[s * 512 + lane + 64 * m];
            acc = fmaf(t.x, t.x, fmaf(t.y, t.y, fmaf(t.z, t.z, fmaf(t.w, t.w, acc))));
        }
#pragma unroll
        for (int o = 1; o < 64; o <<= 1) acc += __shfl_xor(acc, o);
        kk[s] = acc;
    }

    float scr[NSLOT];
    float ssum = 0.f;
#pragma unroll
    for (int s = 0; s < NSLOT; ++s) {
        scr[s] = qscores[(size_t)c * NSLOT + s];
        ssum += scr[s];
    }
    const bool hit = (ssum != 0.0f);

    // fac[s] = scr[s]/kn[s]; comb = (dot/qn)*fac  (algebraically == ref)
    float fac[NSLOT];
#pragma unroll
    for (int s = 0; s < NSLOT; ++s)
        fac[s] = scr[s] / fmaxf(sqrtf(kk[s]), EPSF);

    // each wave processes samples off+wave, off+wave+4, ...
    for (int j = wave; j < cnt; j += 4) {
        const int i = bucket[off + j];
        const f4* q4 = reinterpret_cast<const f4*>(query) + (size_t)i * 512;

        f4 qb[8];
#pragma unroll
        for (int m = 0; m < 8; ++m) qb[m] = q4[lane + 64 * m];

        float qq = 0.f;
        float dot[NSLOT] = {0.f, 0.f, 0.f, 0.f, 0.f};
#pragma unroll
        for (int m = 0; m < 8; ++m) {
            f4 q = qb[m];
            qq = fmaf(q.x, q.x, fmaf(q.y, q.y, fmaf(q.z, q.z, fmaf(q.w, q.w, qq))));
#pragma unroll
            for (int s = 0; s < NSLOT; ++s) {
                f4 t = kls[s * 512 + lane + 64 * m];
                dot[s] = fmaf(q.x, t.x, fmaf(q.y, t.y,
                         fmaf(q.z, t.z, fmaf(q.w, t.w, dot[s]))));
            }
        }

#pragma unroll
        for (int o = 1; o < 64; o <<= 1) {
            qq += __shfl_xor(qq, o);
#pragma unroll
            for (int s = 0; s < NSLOT; ++s) dot[s] += __shfl_xor(dot[s], o);
        }

        float qn = fmaxf(sqrtf(qq), EPSF);
        float comb[NSLOT];
#pragma unroll
        for (int s = 0; s < NSLOT; ++s) comb[s] = (dot[s] / qn) * fac[s];

        // top-k descending; ties -> lowest index
        bool used[NSLOT];
#pragma unroll
        for (int s = 0; s < NSLOT; ++s) used[s] = false;
        float tsc[NSLOT];
        int   tix[NSLOT];
#pragma unroll
        for (int jj = 0; jj < NSLOT; ++jj) {
            float best = -INFINITY;
            int bi = 0;
            if (jj < k) {
#pragma unroll
                for (int s = 0; s < NSLOT; ++s) {
                    if (!used[s] && comb[s] > best) { best = comb[s]; bi = s; }
                }
#pragma unroll
                for (int s = 0; s < NSLOT; ++s) used[s] = used[s] || (s == bi);
            }
            tsc[jj] = best;
            tix[jj] = bi;
        }

        float m0 = tsc[0];
        float esum = 0.f, wsum = 0.f;
        float a[NSLOT];
#pragma unroll
        for (int jj = 0; jj < NSLOT; ++jj) {
            if (jj < k) {
                a[jj] = __expf((tsc[jj] - m0) * 10.0f);   // 1/TEMP = 10
                esum += a[jj];
                wsum += tsc[jj];
            } else {
                a[jj] = 0.f;
            }
        }
        float inv = hit ? (1.0f / esum) : 0.0f;

        float wgt[NSLOT];
#pragma unroll
        for (int s = 0; s < NSLOT; ++s) {
            float ws = 0.f;
#pragma unroll
            for (int jj = 0; jj < NSLOT; ++jj)
                if (jj < k && tix[jj] == s) ws += a[jj] * inv;
            wgt[s] = ws;
        }

        if (lane == 0) out_w[i] = hit ? (wsum / (float)k) : 0.0f;

        // pass 2: only selected rows (wave-uniform branch), vals L2-resident
        f4 acc[8];
#pragma unroll
        for (int m = 0; m < 8; ++m) acc[m] = (f4)(0.f);
#pragma unroll
        for (int s = 0; s < NSLOT; ++s) {
            if (wgt[s] != 0.f) {
                const f4* vp = vc + s * 512 + lane;
#pragma unroll
                for (int m = 0; m < 8; ++m) {
                    f4 v = vp[64 * m];
                    acc[m] += v * wgt[s];
                }
            }
        }
        f4* o4 = reinterpret_cast<f4*>(out_ret) + (size_t)i * 512 + lane;
#pragma unroll
        for (int m = 0; m < 8; ++m) o4[64 * m] = acc[m];
    }
}

// ---------------- generic fallback (any D), sample-centric ----------------

__global__ __launch_bounds__(64) void mb_generic_kernel(
    const float* __restrict__ query,
    const int*   __restrict__ labels,
    const float* __restrict__ mkeys,
    const float* __restrict__ mvals,
    const float* __restrict__ qscores,
    const int*   __restrict__ topk_p,
    float* __restrict__ out_ret,
    float* __restrict__ out_w,
    int B, int n4)
{
    const int lane = threadIdx.x;
    const int i    = blockIdx.x;
    if (i >= B) return;
    const int c = labels[i];
    int k = topk_p[0];
    if (k > NSLOT) k = NSLOT;
    if (k < 1) k = 1;

    const f4* q4 = reinterpret_cast<const f4*>(query) + (size_t)i * n4;
    const f4* k4 = reinterpret_cast<const f4*>(mkeys) + (size_t)c * NSLOT * n4;
    const f4* v4 = reinterpret_cast<const f4*>(mvals) + (size_t)c * NSLOT * n4;
    f4*       o4 = reinterpret_cast<f4*>(out_ret) + (size_t)i * n4;

    float qq = 0.f, dot[NSLOT] = {0}, kk[NSLOT] = {0};
    for (int idx = lane; idx < n4; idx += 64) {
        f4 q = q4[idx];
        qq = fmaf(q.x, q.x, fmaf(q.y, q.y, fmaf(q.z, q.z, fmaf(q.w, q.w, qq))));
        for (int s = 0; s < NSLOT; ++s) {
            f4 t = k4[s * n4 + idx];
            dot[s] = fmaf(q.x, t.x, fmaf(q.y, t.y, fmaf(q.z, t.z, fmaf(q.w, t.w, dot[s]))));
            kk[s]  = fmaf(t.x, t.x, fmaf(t.y, t.y, fmaf(t.z, t.z, fmaf(t.w, t.w, kk[s]))));
        }
    }
    for (int o = 1; o < 64; o <<= 1) {
        qq += __shfl_xor(qq, o);
        for (int s = 0; s < NSLOT; ++s) {
            dot[s] += __shfl_xor(dot[s], o);
            kk[s]  += __shfl_xor(kk[s], o);
        }
    }
    float qn = fmaxf(sqrtf(qq), EPSF);
    float scr[NSLOT], ssum = 0.f;
    for (int s = 0; s < NSLOT; ++s) { scr[s] = qscores[(size_t)c * NSLOT + s]; ssum += scr[s]; }
    float comb[NSLOT];
    for (int s = 0; s < NSLOT; ++s)
        comb[s] = (dot[s] / (qn * fmaxf(sqrtf(kk[s]), EPSF))) * scr[s];
    bool used[NSLOT] = {false, false, false, false, false};
    float tsc[NSLOT]; int tix[NSLOT];
    for (int j = 0; j < NSLOT; ++j) {
        float best = -INFINITY; int bi = 0;
        if (j < k) {
            for (int s = 0; s < NSLOT; ++s)
                if (!used[s] && comb[s] > best) { best = comb[s]; bi = s; }
            used[bi] = true;
        }
        tsc[j] = best; tix[j] = bi;
    }
    const bool hit = (ssum != 0.0f);
    float m = tsc[0], esum = 0.f, wsum = 0.f, a[NSLOT];
    for (int j = 0; j < NSLOT; ++j) {
        if (j < k) { a[j] = __expf((tsc[j] - m) * 10.0f); esum += a[j]; wsum += tsc[j]; }
        else a[j] = 0.f;
    }
    float inv = hit ? (1.0f / esum) : 0.0f;
    float w[NSLOT];
    for (int s = 0; s < NSLOT; ++s) {
        float ws = 0.f;
        for (int j = 0; j < NSLOT; ++j) if (j < k && tix[j] == s) ws += a[j] * inv;
        w[s] = ws;
    }
    if (lane == 0) out_w[i] = hit ? (wsum / (float)k) : 0.0f;
    for (int idx = lane; idx < n4; idx += 64) {
        f4 acc = (f4)(0.f);
        for (int s = 0; s < NSLOT; ++s) {
            f4 v = v4[s * n4 + idx];
            acc += v * w[s];
        }
        o4[idx] = acc;
    }
}

extern "C" void kernel_launch(void* const* d_in, const int* in_sizes, int n_in,
                              void* d_out, int out_size, void* d_ws, size_t ws_size,
                              hipStream_t stream) {
    const float* query   = (const float*)d_in[0];
    const int*   labels  = (const int*)d_in[1];
    const float* mkeys   = (const float*)d_in[2];
    const float* mvals   = (const float*)d_in[3];
    const float* qscores = (const float*)d_in[4];
    const int*   topk    = (const int*)d_in[5];

    const int B  = in_sizes[1];
    const int D  = in_sizes[0] / B;
    const int n4 = D >> 2;
    const int C  = in_sizes[4] / NSLOT;   // qscores is C x S

    float* out_ret = (float*)d_out;
    float* out_w   = out_ret + (size_t)B * D;

    if (D == 2048 && (size_t)(3 * C + B) * sizeof(int) <= ws_size) {
        int* counts  = (int*)d_ws;
        int* offsets = counts + C;
        int* cursor  = offsets + C;
        int* bucket  = cursor + C;

        hipMemsetAsync(counts, 0, (size_t)C * sizeof(int), stream);
        hist_kernel<<<dim3((B + 255) / 256), dim3(256), 0, stream>>>(labels, counts, B);
        scan_kernel<<<dim3(1), dim3(1024), 0, stream>>>(counts, offsets, cursor, C);
        scatter_kernel<<<dim3((B + 255) / 256), dim3(256), 0, stream>>>(labels, cursor, bucket, B);
        mb_class_kernel<<<dim3(C), dim3(256), 0, stream>>>(
            query, mkeys, mvals, qscores, topk, counts, offsets, bucket, out_ret, out_w);
    } else {
        mb_generic_kernel<<<dim3(B), dim3(64), 0, stream>>>(
            query, labels, mkeys, mvals, qscores, topk, out_ret, out_w, B, n4);
    }
}

// Round 7
// 40.419 us; speedup vs baseline: 3.5410x; 3.5410x over previous
//
#include <hip/hip_runtime.h>
#include <math.h>

#define NSLOT 5
#define EPSF 1e-8f
#define WPB 4

typedef float f4 __attribute__((ext_vector_type(4)));

// ---------------- binning kernels ----------------

__global__ void hist_kernel(const int* __restrict__ labels, int* __restrict__ counts, int B) {
    int i = blockIdx.x * blockDim.x + threadIdx.x;
    if (i < B) atomicAdd(&counts[labels[i]], 1);
}

__global__ void scan_kernel(const int* __restrict__ counts, int* __restrict__ cursor, int C) {
    __shared__ int sh[1024];
    __shared__ int running;
    if (threadIdx.x == 0) running = 0;
    __syncthreads();
    for (int base = 0; base < C; base += 1024) {
        int t = base + threadIdx.x;
        int v = (t < C) ? counts[t] : 0;
        sh[threadIdx.x] = v;
        __syncthreads();
        for (int d = 1; d < 1024; d <<= 1) {
            int x = (threadIdx.x >= d) ? sh[threadIdx.x - d] : 0;
            __syncthreads();
            sh[threadIdx.x] += x;
            __syncthreads();
        }
        int excl = sh[threadIdx.x] - v + running;
        if (t < C) cursor[t] = excl;
        __syncthreads();
        if (threadIdx.x == 0) running += sh[1023];
        __syncthreads();
    }
}

__global__ void scatter_kernel(const int* __restrict__ labels, int* __restrict__ cursor,
                               int* __restrict__ bucket, int B) {
    int i = blockIdx.x * blockDim.x + threadIdx.x;
    if (i < B) {
        int slot = atomicAdd(&cursor[labels[i]], 1);
        bucket[slot] = i;
    }
}

// ---------------- main kernel: wave-per-sample over label-sorted order ----------------
// Block b, wave w -> sorted position j = (b&7)*(B/8) + (b>>3)*WPB + w.
// With round-robin block->XCD dispatch, XCD x gets blocks {x, x+8, ...} which
// cover the contiguous sorted stripe [x*B/8, (x+1)*B/8): each class's samples
// are processed consecutively on ONE XCD -> keys/vals fetched once, then L2-hit.

template<int N4T>
__global__ __launch_bounds__(64 * WPB, 4) void mb_wave_kernel(
    const float* __restrict__ query,
    const float* __restrict__ mkeys,
    const float* __restrict__ mvals,
    const float* __restrict__ qscores,
    const int*   __restrict__ topk_p,
    const int*   __restrict__ labels,
    const int*   __restrict__ bucket,   // nullptr -> identity (no binning)
    float* __restrict__ out_ret,
    float* __restrict__ out_w,
    int B, int n4_rt)
{
    const int tid  = threadIdx.x;
    const int lane = tid & 63;
    const int wave = tid >> 6;

    int j;
    if (bucket) {
        const int stripe = B >> 3;            // B/8 per XCD (B % 32 == 0 guaranteed)
        j = (blockIdx.x & 7) * stripe + (blockIdx.x >> 3) * WPB + wave;
    } else {
        j = blockIdx.x * WPB + wave;
    }
    if (j >= B) return;
    const int i = bucket ? bucket[j] : j;
    const int c = labels[i];

    int k = topk_p[0];
    if (k > NSLOT) k = NSLOT;
    if (k < 1) k = 1;

    const int n4 = (N4T > 0) ? N4T : n4_rt;
    const f4* q4 = reinterpret_cast<const f4*>(query) + (size_t)i * n4;
    const f4* k4 = reinterpret_cast<const f4*>(mkeys) + (size_t)c * NSLOT * n4;
    const f4* v4 = reinterpret_cast<const f4*>(mvals) + (size_t)c * NSLOT * n4;
    f4*       o4 = reinterpret_cast<f4*>(out_ret) + (size_t)i * n4;

    // ---- pass 1: qq, dot[s], kk[s] in one sweep ----
    float qq = 0.f;
    float dot[NSLOT], kk[NSLOT];
#pragma unroll
    for (int s = 0; s < NSLOT; ++s) { dot[s] = 0.f; kk[s] = 0.f; }

    for (int idx = lane; idx < n4; idx += 64) {
        f4 q = q4[idx];
        qq = fmaf(q.x, q.x, fmaf(q.y, q.y, fmaf(q.z, q.z, fmaf(q.w, q.w, qq))));
#pragma unroll
        for (int s = 0; s < NSLOT; ++s) {
            f4 kv = k4[s * n4 + idx];
            dot[s] = fmaf(q.x, kv.x, fmaf(q.y, kv.y, fmaf(q.z, kv.z, fmaf(q.w, kv.w, dot[s]))));
            kk[s]  = fmaf(kv.x, kv.x, fmaf(kv.y, kv.y, fmaf(kv.z, kv.z, fmaf(kv.w, kv.w, kk[s]))));
        }
    }

    // ---- butterfly reduce: every lane gets totals ----
#pragma unroll
    for (int off = 1; off < 64; off <<= 1) {
        qq += __shfl_xor(qq, off);
#pragma unroll
        for (int s = 0; s < NSLOT; ++s) {
            dot[s] += __shfl_xor(dot[s], off);
            kk[s]  += __shfl_xor(kk[s], off);
        }
    }

    // ---- scalar epilogue (all lanes redundantly) ----
    float qn = fmaxf(sqrtf(qq), EPSF);

    float scr[NSLOT];
    float ssum = 0.f;
#pragma unroll
    for (int s = 0; s < NSLOT; ++s) {
        scr[s] = qscores[(size_t)c * NSLOT + s];
        ssum += scr[s];
    }

    float comb[NSLOT];
#pragma unroll
    for (int s = 0; s < NSLOT; ++s) {
        float kn = fmaxf(sqrtf(kk[s]), EPSF);
        comb[s] = (dot[s] / (qn * kn)) * scr[s];
    }

    // top-k descending; ties -> lowest index
    bool used[NSLOT];
#pragma unroll
    for (int s = 0; s < NSLOT; ++s) used[s] = false;
    float tsc[NSLOT];
    int   tix[NSLOT];
#pragma unroll
    for (int jj = 0; jj < NSLOT; ++jj) {
        float best = -INFINITY;
        int bi = 0;
        if (jj < k) {
#pragma unroll
            for (int s = 0; s < NSLOT; ++s) {
                if (!used[s] && comb[s] > best) { best = comb[s]; bi = s; }
            }
#pragma unroll
            for (int s = 0; s < NSLOT; ++s) used[s] = used[s] || (s == bi);
        }
        tsc[jj] = best;
        tix[jj] = bi;
    }

    const bool hit = (ssum != 0.0f);
    float m = tsc[0];
    float esum = 0.f, wsum = 0.f;
    float a[NSLOT];
#pragma unroll
    for (int jj = 0; jj < NSLOT; ++jj) {
        if (jj < k) {
            a[jj] = __expf((tsc[jj] - m) * 10.0f);   // 1/TEMP = 10
            esum += a[jj];
            wsum += tsc[jj];
        } else {
            a[jj] = 0.f;
        }
    }
    float inv = hit ? (1.0f / esum) : 0.0f;

    float wgt[NSLOT];
#pragma unroll
    for (int s = 0; s < NSLOT; ++s) {
        float ws = 0.f;
#pragma unroll
        for (int jj = 0; jj < NSLOT; ++jj)
            if (jj < k && tix[jj] == s) ws += a[jj] * inv;
        wgt[s] = ws;
    }

    if (lane == 0) out_w[i] = hit ? (wsum / (float)k) : 0.0f;

    // ---- pass 2: out = sum_s wgt[s] * vals[s] (uniform, spill-free) ----
    for (int idx = lane; idx < n4; idx += 64) {
        f4 acc = (f4)(0.f);
#pragma unroll
        for (int s = 0; s < NSLOT; ++s) {
            f4 v = v4[s * n4 + idx];
            acc.x = fmaf(wgt[s], v.x, acc.x);
            acc.y = fmaf(wgt[s], v.y, acc.y);
            acc.z = fmaf(wgt[s], v.z, acc.z);
            acc.w = fmaf(wgt[s], v.w, acc.w);
        }
        o4[idx] = acc;
    }
}

extern "C" void kernel_launch(void* const* d_in, const int* in_sizes, int n_in,
                              void* d_out, int out_size, void* d_ws, size_t ws_size,
                              hipStream_t stream) {
    const float* query   = (const float*)d_in[0];
    const int*   labels  = (const int*)d_in[1];
    const float* mkeys   = (const float*)d_in[2];
    const float* mvals   = (const float*)d_in[3];
    const float* qscores = (const float*)d_in[4];
    const int*   topk    = (const int*)d_in[5];

    const int B  = in_sizes[1];
    const int D  = in_sizes[0] / B;
    const int n4 = D >> 2;
    const int C  = in_sizes[4] / NSLOT;

    float* out_ret = (float*)d_out;
    float* out_w   = out_ret + (size_t)B * D;

    const bool can_bin = (B % 32 == 0) &&
                         ((size_t)(2 * C + B) * sizeof(int) <= ws_size);

    const int* bucket = nullptr;
    if (can_bin) {
        int* counts = (int*)d_ws;           // reused as cursor after scan
        int* bkt    = counts + 2 * C;       // [B]
        hipMemsetAsync(counts, 0, (size_t)C * sizeof(int), stream);
        hist_kernel<<<dim3((B + 255) / 256), dim3(256), 0, stream>>>(labels, counts, B);
        scan_kernel<<<dim3(1), dim3(1024), 0, stream>>>(counts, counts + C, C);
        scatter_kernel<<<dim3((B + 255) / 256), dim3(256), 0, stream>>>(labels, counts + C, bkt, B);
        bucket = bkt;
    }

    dim3 grid((B + WPB - 1) / WPB), block(64 * WPB);
    if (D == 2048) {
        mb_wave_kernel<512><<<grid, block, 0, stream>>>(
            query, mkeys, mvals, qscores, topk, labels, bucket, out_ret, out_w, B, n4);
    } else if (D == 1024) {
        mb_wave_kernel<256><<<grid, block, 0, stream>>>(
            query, mkeys, mvals, qscores, topk, labels, bucket, out_ret, out_w, B, n4);
    } else {
        mb_wave_kernel<0><<<grid, block, 0, stream>>>(
            query, mkeys, mvals, qscores, topk, labels, bucket, out_ret, out_w, B, n4);
    }
}